// Round 11
// baseline (254.842 us; speedup 1.0000x reference)
//
#include <hip/hip_runtime.h>

#define NT 128
#define SS 512
#define PW 132                         // padded per-wave partial-row stride (floats)
#define NW 8                           // waves per block (8-way row split)

typedef float f32x2 __attribute__((ext_vector_type(2)));

__device__ __forceinline__ float rdlane(float v, int lane) {
    return __int_as_float(__builtin_amdgcn_readlane(__float_as_int(v), lane));
}
__device__ __forceinline__ int fexp_of(float x) {
    return (int)((__float_as_uint(x) >> 23) & 0xFFu) - 127;
}
// barrier draining only LDS ops — global prefetches stay in flight
__device__ __forceinline__ void lds_barrier() {
    asm volatile("s_waitcnt lgkmcnt(0)\n\ts_barrier" ::: "memory");
}

__global__ void zero_out_kernel(float* out) { out[0] = 0.0f; }

__global__ __launch_bounds__(512, 1) void crf_fwd_kernel(
    const float* __restrict__ emissions,        // [B, S, NT] f32
    const int* __restrict__ tags,               // [B, S]
    const unsigned char* __restrict__ mask,     // [B, S]
    const float* __restrict__ trans,            // [NT, NT] f32
    float* __restrict__ out)                    // [1] f32
{
    const int b   = blockIdx.x;                 // one batch per block
    const int tid = threadIdx.x;                // 0..511
    const int l   = tid & 63;
    const int w   = tid >> 6;                   // wave 0..7: rows/states 16w..16w+15
    const int st  = (w << 4) + (l & 15);        // owned state (4x dup per wave)

    __shared__ float pbuf[2][NW * PW];          // [parity][wave*PW + col]
    __shared__ int   kbuf[NW];
    __shared__ float redf[NW];
    __shared__ float redg[NW];

    const float*         emB = emissions + (size_t)b * SS * NT;
    const int*           tgB = tags + b * SS;
    const unsigned char* mkB = mask + b * SS;

    // ---- gold score fully hoisted off the recursion (1 step/thread) ----
    float gold = 0.0f;
    {
        int t    = tid;                          // SS == 512 == blockDim
        int tg   = tgB[t];
        float mk = mkB[t] ? 1.0f : 0.0f;
        float a  = emB[(size_t)t * NT + tg];
        if (t > 0) a += trans[tgB[t - 1] * NT + tg];
        gold = a * mk;
    }

    // ---- expT: own 16 rows, cols {l, l+64} packed -> 32 VGPRs ----
    f32x2 eTr[16];
    #pragma unroll
    for (int r = 0; r < 16; r++) {
        const float* row = trans + (size_t)((w << 4) + r) * NT;
        f32x2 v; v.x = __expf(row[l]); v.y = __expf(row[l + 64]);
        eTr[r] = v;
    }

    // ---- init: true alpha_j = p̂ * 2^S * e^{M0} (S global) ----
    float a0 = emB[st];
    {
        float v = a0;                            // max over 16 distinct states
        #pragma unroll
        for (int o = 8; o > 0; o >>= 1) v = fmaxf(v, __shfl_xor(v, o));
        if (l == 0) redf[w] = v;
    }
    __syncthreads();
    float M0;
    {
        float m01 = fmaxf(redf[0], redf[1]), m23 = fmaxf(redf[2], redf[3]);
        float m45 = fmaxf(redf[4], redf[5]), m67 = fmaxf(redf[6], redf[7]);
        M0 = fmaxf(fmaxf(m01, m23), fmaxf(m45, m67));
    }

    float p = __expf(a0 - M0);                  // p̂ for state st (duplicated)
    float S = 0.0f;
    int K = 0, kv_own = 0;

    // ---- emission pipeline: loads 4 deep, exp 2 steps off-chain ----
    float ex_o = __expf(emB[(size_t)1 * NT + st]);   // exp(e_1)
    float ex_e = __expf(emB[(size_t)2 * NT + st]);   // exp(e_2)
    float pd_o = emB[(size_t)3 * NT + st];
    float pd_e = emB[(size_t)4 * NT + st];

    // matvec over own 16 rows + 8-way partial combine; 1 lgkm barrier
    auto matvec = [&](int q, bool kw) -> float {
        f32x2 A0 = {0.f,0.f}, A1 = {0.f,0.f}, A2 = {0.f,0.f}, A3 = {0.f,0.f};
        #pragma unroll
        for (int r = 0; r < 16; r += 4) {
            float q0 = rdlane(p, r + 0);
            float q1 = rdlane(p, r + 1);
            float q2 = rdlane(p, r + 2);
            float q3 = rdlane(p, r + 3);
            f32x2 b0 = {q0, q0}, b1 = {q1, q1}, b2 = {q2, q2}, b3 = {q3, q3};
            A0 = __builtin_elementwise_fma(b0, eTr[r + 0], A0);
            A1 = __builtin_elementwise_fma(b1, eTr[r + 1], A1);
            A2 = __builtin_elementwise_fma(b2, eTr[r + 2], A2);
            A3 = __builtin_elementwise_fma(b3, eTr[r + 3], A3);
        }
        f32x2 s2 = (A0 + A1) + (A2 + A3);       // {partial col l, partial col l+64}
        pbuf[q][w * PW + l]      = s2.x;
        pbuf[q][w * PW + l + 64] = s2.y;
        if (kw && l == 0) kbuf[w] = kv_own;     // rides the barrier
        lds_barrier();                          // lgkm-only: vmcnt untouched
        float r0 = pbuf[q][0 * PW + st], r1 = pbuf[q][1 * PW + st];
        float r2 = pbuf[q][2 * PW + st], r3 = pbuf[q][3 * PW + st];
        float r4 = pbuf[q][4 * PW + st], r5 = pbuf[q][5 * PW + st];
        float r6 = pbuf[q][6 * PW + st], r7 = pbuf[q][7 * PW + st];
        return ((r0 + r1) + (r2 + r3)) + ((r4 + r5) + (r6 + r7));
    };
    auto rot = [&](int t, float& pd, float& ex) {
        float nr = pd;
        int tn = t + 4; if (tn > SS - 1) tn = SS - 1;
        pd = emB[(size_t)tn * NT + st];
        ex = __expf(nr);
    };

    // ---- forward recursion: groups of 4 steps; rescale at sub-step 0 ----
    #pragma unroll 1
    for (int t = 1; t < SS; t += 4) {
        {   // sub 0 (parity 1): apply K, propose next kv (shuffles 1x/group)
            float sn = matvec(1, false) * ex_o;
            p = ldexpf(sn, -K);
            S += (float)K;
            int kv = fexp_of(p);
            #pragma unroll
            for (int o = 8; o > 0; o >>= 1) kv = max(kv, __shfl_xor(kv, o));
            kv_own = kv;
            rot(t, pd_o, ex_o);
        }
        if (t + 1 < SS) {   // sub 1 (parity 0): K exchange piggyback
            float sn = matvec(0, true) * ex_e;
            int k0 = max(kbuf[0], kbuf[1]), k1 = max(kbuf[2], kbuf[3]);
            int k2 = max(kbuf[4], kbuf[5]), k3 = max(kbuf[6], kbuf[7]);
            K = max(max(k0, k1), max(k2, k3));
            p = sn;
            rot(t + 1, pd_e, ex_e);
        }
        if (t + 2 < SS) { p = matvec(1, false) * ex_o; rot(t + 2, pd_o, ex_o); }
        if (t + 3 < SS) { p = matvec(0, false) * ex_e; rot(t + 3, pd_e, ex_e); }
    }

    // ---- epilogue: partition = M0 + S*ln2 + log Σ p̂ ; reduce gold ----
    {
        float sw = (l < 16) ? p : 0.0f;         // states duplicated 4x per wave
        float g  = gold;
        #pragma unroll
        for (int o = 32; o > 0; o >>= 1) {
            sw += __shfl_xor(sw, o);
            g  += __shfl_xor(g, o);
        }
        if (l == 0) { redf[w] = sw; redg[w] = g; }
    }
    __syncthreads();
    if (tid == 0) {
        float tot = ((redf[0] + redf[1]) + (redf[2] + redf[3])) +
                    ((redf[4] + redf[5]) + (redf[6] + redf[7]));
        float gt  = ((redg[0] + redg[1]) + (redg[2] + redg[3])) +
                    ((redg[4] + redg[5]) + (redg[6] + redg[7]));
        float part = M0 + S * 0.69314718055994531f + __logf(tot);
        atomicAdd(out, part - gt);
    }
}

extern "C" void kernel_launch(void* const* d_in, const int* in_sizes, int n_in,
                              void* d_out, int out_size, void* d_ws, size_t ws_size,
                              hipStream_t stream) {
    const float*         emissions = (const float*)d_in[0];
    const int*           tags      = (const int*)d_in[1];
    const unsigned char* mask      = (const unsigned char*)d_in[2];
    const float*         trans     = (const float*)d_in[3];
    float*               out       = (float*)d_out;

    zero_out_kernel<<<1, 1, 0, stream>>>(out);
    crf_fwd_kernel<<<256, 512, 0, stream>>>(emissions, tags, mask, trans, out);
}